// Round 2
// baseline (62.695 us; speedup 1.0000x reference)
//
#include <hip/hip_runtime.h>
#include <stdint.h>
#include <string.h>

// JAX >= 0.4.36 defaults jax_threefry_partitionable=True (counter = (0, i),
// output = w0 ^ w1). Validated bit-exact in round 1 (absmax 0.0).
#define JAX_THREEFRY_PARTITIONABLE 1

#define DIN 100
#define DHID 512
#define DOUT 200
#define NPATH_AGG 5
#define NFINAL 10
#define MAXLEN 4
#define NSLOT (MAXLEN * NFINAL)   // 40 final (t, walk) slots
#define NE 16                     // dedup'd agg entries: [0]=start(x5), 1..15=steps

struct RngConsts {
  uint32_t kA[3][2];        // fold_in(fold_in(key(42),0), j), j=0..2
  int      starts2[NFINAL]; // jax.random.randint(fold_in(kw,1),(10,),0,N)
  float    u2[3][NFINAL];   // uniforms for the 10 final walks, steps 0..2
  int      N, maxd_bi, maxd_dir;
};

// ---------------- Threefry-2x32 (20 rounds), exactly as in jax._src.prng ---
__host__ __device__ inline void tf2x32(uint32_t k0, uint32_t k1,
                                       uint32_t& x0, uint32_t& x1) {
  const uint32_t k2 = k0 ^ k1 ^ 0x1BD11BDAu;
  x0 += k0; x1 += k1;
#define TFR(r) { x0 += x1; x1 = (x1 << (r)) | (x1 >> (32 - (r))); x1 ^= x0; }
  TFR(13) TFR(15) TFR(26) TFR(6)
  x0 += k1; x1 += k2 + 1u;
  TFR(17) TFR(29) TFR(16) TFR(24)
  x0 += k2; x1 += k0 + 2u;
  TFR(13) TFR(15) TFR(26) TFR(6)
  x0 += k0; x1 += k1 + 3u;
  TFR(17) TFR(29) TFR(16) TFR(24)
  x0 += k1; x1 += k2 + 4u;
  TFR(13) TFR(15) TFR(26) TFR(6)
  x0 += k2; x1 += k0 + 5u;
#undef TFR
}

__host__ __device__ inline uint32_t jax_bits32(uint32_t k0, uint32_t k1,
                                               uint32_t idx, uint32_t half) {
#if JAX_THREEFRY_PARTITIONABLE
  (void)half;
  uint32_t x0 = 0u, x1 = idx;   // 64-bit counter i -> (hi, lo) = (0, i)
  tf2x32(k0, k1, x0, x1);
  return x0 ^ x1;
#else
  uint32_t x0, x1;
  const bool lo = idx < half;
  if (lo) { x0 = idx;        x1 = idx + half; }
  else    { x0 = idx - half; x1 = idx;        }
  tf2x32(k0, k1, x0, x1);
  return lo ? x0 : x1;
#endif
}

__host__ __device__ inline float bits_to_unif(uint32_t bits) {
  uint32_t f = (bits >> 9) | 0x3F800000u;
  float r;
  memcpy(&r, &f, 4);
  return r - 1.0f;
}

// ---------------- Wave-parallel speculative walk step ----------------------
// cur/valid are wave-uniform. Lanes preload the neighbor row concurrently
// with the degree load; the chosen column is shfl'd after deg arrives.
__device__ __forceinline__ void walk_step(const int* __restrict__ nbr,
                                          const int* __restrict__ deg,
                                          int maxd, int lane, float u,
                                          int& cur, int& valid) {
  const int d = deg[cur];
  const long long base = (long long)cur * maxd;
  int r0 = 0, r1 = 0, r2 = 0, r3 = 0;
  if (lane < maxd)       r0 = nbr[base + lane];
  if (lane + 64 < maxd)  r1 = nbr[base + lane + 64];
  if (lane + 128 < maxd) r2 = nbr[base + lane + 128];
  if (lane + 192 < maxd) r3 = nbr[base + lane + 192];
  int c = (int)(u * (float)d);
  const int cm = (d - 1 > 0) ? (d - 1) : 0;
  if (c > cm) c = cm;
  const int cl = c & 63;
  const int v0 = __shfl(r0, cl);
  const int v1 = __shfl(r1, cl);
  const int v2 = __shfl(r2, cl);
  const int v3 = __shfl(r3, cl);
  const int v = (c < 64) ? v0 : (c < 128) ? v1 : (c < 192) ? v2 : v3;
  valid = valid && (d > 0);
  if (valid) cur = v;
}

// ---------------- Kernel 1: the 10 final directed walks (wave per walker) --
__global__ void k_final_walks(const int* __restrict__ nbr_dir,
                              const int* __restrict__ deg_dir,
                              RngConsts rc,
                              int* __restrict__ nodes2,
                              int* __restrict__ masks2) {
  const int w = threadIdx.x >> 6;
  const int lane = threadIdx.x & 63;
  if (w >= NFINAL) return;
  int cur = rc.starts2[w];
  int valid = 1;
  int nj[MAXLEN], mj[MAXLEN];
  nj[0] = cur; mj[0] = 1;
#pragma unroll
  for (int j = 0; j < MAXLEN - 1; ++j) {
    walk_step(nbr_dir, deg_dir, rc.maxd_dir, lane, rc.u2[j][w], cur, valid);
    nj[j + 1] = cur; mj[j + 1] = valid;
  }
  if (lane == 0) {
#pragma unroll
    for (int j = 0; j < MAXLEN; ++j) {
      nodes2[j * NFINAL + w] = nj[j];
      masks2[j * NFINAL + w] = mj[j];
    }
  }
}

// ---------------- Kernel 2: per-slot agg walks + fc1 + mean + fc3 ----------
__global__ __launch_bounds__(DHID) void k_slot(
    const float* __restrict__ x,
    const int* __restrict__ nbr_bi, const int* __restrict__ deg_bi,
    const float* __restrict__ W1, const float* __restrict__ b1,
    const float* __restrict__ W3, const float* __restrict__ b3,
    const int* __restrict__ nodes2, const int* __restrict__ masks2,
    RngConsts rc, float* __restrict__ out2v /* [NSLOT][DOUT] */) {
  __shared__ int   vnode[NE];
  __shared__ int   vmask[NE];
  __shared__ float aggv[DHID];

  const int slot = blockIdx.x;
  if (masks2[slot] == 0) return;          // uniform across block
  const int n = nodes2[slot];
  const int tid = threadIdx.x;
  const int wv = tid >> 6, lane = tid & 63;

  if (tid == 0) { vnode[0] = n; vmask[0] = 1; }
  // 5 agg walks, wave wv < 5 handles walk p=wv; walker id = p*N + n.
  if (wv < NPATH_AGG) {
    const uint32_t wkr = (uint32_t)(wv * rc.N + n);
    int cur = n, valid = 1;
#pragma unroll
    for (int j = 0; j < MAXLEN - 1; ++j) {
      const float u = bits_to_unif(
          jax_bits32(rc.kA[j][0], rc.kA[j][1], wkr, 250000u));
      walk_step(nbr_bi, deg_bi, rc.maxd_bi, lane, u, cur, valid);
      if (lane == 0) {
        vnode[1 + j * NPATH_AGG + wv] = cur;
        vmask[1 + j * NPATH_AGG + wv] = valid;
      }
    }
  }
  __syncthreads();

  // ---- fc1: hidden unit tid; 16 dedup'd entries (start node has weight 5)
  int vn[NE], vm[NE];
#pragma unroll
  for (int e = 0; e < NE; ++e) { vn[e] = vnode[e]; vm[e] = vmask[e]; }
  float cntf = 5.0f;
#pragma unroll
  for (int e = 1; e < NE; ++e) cntf += (float)vm[e];

  const float4* __restrict__ xr[NE];
#pragma unroll
  for (int e = 0; e < NE; ++e)
    xr[e] = (const float4*)(x + (long long)vn[e] * DIN);
  const float4* __restrict__ w1r = (const float4*)(W1 + (long long)tid * DIN);

  float acc[NE];
#pragma unroll
  for (int e = 0; e < NE; ++e) acc[e] = 0.0f;
#pragma unroll 5
  for (int k4 = 0; k4 < DIN / 4; ++k4) {
    const float4 w = w1r[k4];
#pragma unroll
    for (int e = 0; e < NE; ++e) {
      const float4 xv = xr[e][k4];           // broadcast: 1 transaction/wave
      acc[e] += w.x * xv.x + w.y * xv.y + w.z * xv.z + w.w * xv.w;
    }
  }
  const float bb = b1[tid];
  float h0 = acc[0] + bb;
  h0 = (h0 > 0.0f) ? h0 : 0.0f;
  float hs = 5.0f * h0;
#pragma unroll
  for (int e = 1; e < NE; ++e) {
    if (vm[e]) {
      float hv = acc[e] + bb;
      hs += (hv > 0.0f) ? hv : 0.0f;
    }
  }
  aggv[tid] = hs / cntf;
  __syncthreads();

  // ---- fc3: wave per output o; lanes split K=512 as float4 (coalesced)
  const float4* __restrict__ aggv4 = (const float4*)aggv;
  const float4 a0 = aggv4[lane];
  const float4 a1 = aggv4[64 + lane];
  for (int o = wv; o < DOUT; o += 8) {
    const float4* __restrict__ w4 = (const float4*)(W3 + (long long)o * DHID);
    const float4 g0 = w4[lane];
    const float4 g1 = w4[64 + lane];
    float p = a0.x * g0.x + a0.y * g0.y + a0.z * g0.z + a0.w * g0.w
            + a1.x * g1.x + a1.y * g1.y + a1.z * g1.z + a1.w * g1.w;
#pragma unroll
    for (int off = 32; off; off >>= 1) p += __shfl_xor(p, off);
    if (lane == 0) {
      const float r = p + b3[o];
      out2v[slot * DOUT + o] = (r > 0.0f) ? r : 0.0f;
    }
  }
}

// ---------------- Kernel 3: deterministic masked mean ----------------------
__global__ void k_final(const float* __restrict__ out2v,
                        const int* __restrict__ masks2,
                        float* __restrict__ out) {
  const int o = threadIdx.x;
  if (o >= DOUT) return;
  float s = 0.0f, ws = 0.0f;
  for (int slot = 0; slot < NSLOT; ++slot) {
    if (masks2[slot]) { s += out2v[slot * DOUT + o]; ws += 1.0f; }
  }
  out[o] = s / ws;
}

// ---------------- Host-side PRNG chain -------------------------------------
static void h_enc(const uint32_t k[2], uint32_t x0, uint32_t x1, uint32_t out[2]) {
  tf2x32(k[0], k[1], x0, x1);
  out[0] = x0; out[1] = x1;
}
static void h_foldin(const uint32_t k[2], uint32_t data, uint32_t out[2]) {
  h_enc(k, 0u, data, out);
}

extern "C" void kernel_launch(void* const* d_in, const int* in_sizes, int n_in,
                              void* d_out, int out_size, void* d_ws, size_t ws_size,
                              hipStream_t stream) {
  const float* x       = (const float*)d_in[0];
  const int*   nbr_bi  = (const int*)d_in[2];
  const int*   deg_bi  = (const int*)d_in[3];
  const int*   nbr_dir = (const int*)d_in[4];
  const int*   deg_dir = (const int*)d_in[5];
  const float* W1      = (const float*)d_in[6];
  const float* b1      = (const float*)d_in[7];
  const float* W3      = (const float*)d_in[8];
  const float* b3      = (const float*)d_in[9];

  const int N = in_sizes[0] / DIN;
  RngConsts rc;
  rc.N = N;
  rc.maxd_bi  = in_sizes[2] / N;
  rc.maxd_dir = in_sizes[4] / N;

  const uint32_t kw[2] = {0u, 42u};            // jax.random.key(42)
  uint32_t kA[2];
  h_foldin(kw, 0u, kA);
  for (uint32_t j = 0; j < 3; ++j) h_foldin(kA, j, rc.kA[j]);

  uint32_t kS[2];
  h_foldin(kw, 1u, kS);
  uint32_t k1_[2], k2_[2];
#if JAX_THREEFRY_PARTITIONABLE
  h_enc(kS, 0u, 0u, k1_);
  h_enc(kS, 0u, 1u, k2_);
#else
  {
    uint32_t a[2], b[2];
    h_enc(kS, 0u, 2u, a);
    h_enc(kS, 1u, 3u, b);
    k1_[0] = a[0]; k1_[1] = b[0];
    k2_[0] = a[1]; k2_[1] = b[1];
  }
#endif
  {
    const uint32_t span = (uint32_t)N;
    uint32_t mult = 65536u % span;
    mult = (uint32_t)(mult * mult) % span;
    for (uint32_t i = 0; i < NFINAL; ++i) {
      const uint32_t hi = jax_bits32(k1_[0], k1_[1], i, NFINAL / 2);
      const uint32_t lo = jax_bits32(k2_[0], k2_[1], i, NFINAL / 2);
      uint32_t off = (hi % span) * mult + (lo % span);
      off %= span;
      rc.starts2[i] = (int)off;
    }
  }

  uint32_t kP[2];
  h_foldin(kw, 2u, kP);
  for (uint32_t j = 0; j < 3; ++j) {
    uint32_t kPj[2];
    h_foldin(kP, j, kPj);
    for (uint32_t i = 0; i < NFINAL; ++i)
      rc.u2[j][i] = bits_to_unif(jax_bits32(kPj[0], kPj[1], i, NFINAL / 2));
  }

  // Workspace layout: nodes2[40] | masks2[40] | out2v[40*200]
  int*   nodes2 = (int*)d_ws;
  int*   masks2 = nodes2 + NSLOT;
  float* out2v  = (float*)(masks2 + NSLOT);

  k_final_walks<<<1, NFINAL * 64, 0, stream>>>(nbr_dir, deg_dir, rc,
                                               nodes2, masks2);
  k_slot<<<NSLOT, DHID, 0, stream>>>(x, nbr_bi, deg_bi, W1, b1, W3, b3,
                                     nodes2, masks2, rc, out2v);
  k_final<<<1, 256, 0, stream>>>(out2v, masks2, (float*)d_out);
}

// Round 3
// 27.254 us; speedup vs baseline: 2.3004x; 2.3004x over previous
//
#include <hip/hip_runtime.h>
#include <stdint.h>
#include <string.h>

// JAX >= 0.4.36 partitionable threefry. Validated bit-exact (absmax 0.0, r1/r2).
#define JAX_THREEFRY_PARTITIONABLE 1

#define DIN 100
#define DHID 512
#define DOUT 200
#define NPATH_AGG 5
#define NFINAL 10
#define MAXLEN 4
#define NSLOT (MAXLEN * NFINAL)   // 40 final (t, walk) slots
#define NE 16                     // dedup'd agg entries: [0]=start(x5), 1..15=steps

struct RngConsts {
  uint32_t kA[3][2];        // fold_in(fold_in(key(42),0), j), j=0..2
  int      starts2[NFINAL]; // jax.random.randint(fold_in(kw,1),(10,),0,N)
  float    u2[3][NFINAL];   // uniforms for the 10 final walks, steps 0..2
  int      N, maxd_bi, maxd_dir;
};

// ---------------- Threefry-2x32 (20 rounds), exactly as in jax._src.prng ---
__host__ __device__ inline void tf2x32(uint32_t k0, uint32_t k1,
                                       uint32_t& x0, uint32_t& x1) {
  const uint32_t k2 = k0 ^ k1 ^ 0x1BD11BDAu;
  x0 += k0; x1 += k1;
#define TFR(r) { x0 += x1; x1 = (x1 << (r)) | (x1 >> (32 - (r))); x1 ^= x0; }
  TFR(13) TFR(15) TFR(26) TFR(6)
  x0 += k1; x1 += k2 + 1u;
  TFR(17) TFR(29) TFR(16) TFR(24)
  x0 += k2; x1 += k0 + 2u;
  TFR(13) TFR(15) TFR(26) TFR(6)
  x0 += k0; x1 += k1 + 3u;
  TFR(17) TFR(29) TFR(16) TFR(24)
  x0 += k1; x1 += k2 + 4u;
  TFR(13) TFR(15) TFR(26) TFR(6)
  x0 += k2; x1 += k0 + 5u;
#undef TFR
}

__host__ __device__ inline uint32_t jax_bits32(uint32_t k0, uint32_t k1,
                                               uint32_t idx, uint32_t half) {
#if JAX_THREEFRY_PARTITIONABLE
  (void)half;
  uint32_t x0 = 0u, x1 = idx;   // 64-bit counter i -> (hi, lo) = (0, i)
  tf2x32(k0, k1, x0, x1);
  return x0 ^ x1;
#else
  uint32_t x0, x1;
  const bool lo = idx < half;
  if (lo) { x0 = idx;        x1 = idx + half; }
  else    { x0 = idx - half; x1 = idx;        }
  tf2x32(k0, k1, x0, x1);
  return lo ? x0 : x1;
#endif
}

__host__ __device__ inline float bits_to_unif(uint32_t bits) {
  uint32_t f = (bits >> 9) | 0x3F800000u;
  float r;
  memcpy(&r, &f, 4);
  return r - 1.0f;
}

// ---------------- Wave-parallel speculative walk step ----------------------
// cur/valid wave-uniform. Neighbor row preloaded concurrently with degree.
__device__ __forceinline__ void walk_step(const int* __restrict__ nbr,
                                          const int* __restrict__ deg,
                                          int maxd, int lane, float u,
                                          int& cur, int& valid) {
  const int d = deg[cur];
  const long long base = (long long)cur * maxd;
  int r0 = 0, r1 = 0, r2 = 0, r3 = 0;
  if (lane < maxd)       r0 = nbr[base + lane];
  if (lane + 64 < maxd)  r1 = nbr[base + lane + 64];
  if (lane + 128 < maxd) r2 = nbr[base + lane + 128];
  if (lane + 192 < maxd) r3 = nbr[base + lane + 192];
  int c = (int)(u * (float)d);
  const int cm = (d - 1 > 0) ? (d - 1) : 0;
  if (c > cm) c = cm;
  const int cl = c & 63;
  const int v0 = __shfl(r0, cl);
  const int v1 = __shfl(r1, cl);
  const int v2 = __shfl(r2, cl);
  const int v3 = __shfl(r3, cl);
  int v = (c < 64) ? v0 : (c < 128) ? v1 : (c < 192) ? v2 : v3;
  if (c >= 256) v = nbr[base + c];     // safety net (wave-uniform load)
  valid = valid && (d > 0);
  if (valid) cur = v;
}

// ---------------- Kernel A: per-slot {final-walk prefix, agg walks, fc1} ---
// Writes maskArr[slot] and aggAll[slot][DHID].
__global__ __launch_bounds__(DHID) void k_slot(
    const float* __restrict__ x,
    const int* __restrict__ nbr_bi, const int* __restrict__ deg_bi,
    const int* __restrict__ nbr_dir, const int* __restrict__ deg_dir,
    const float* __restrict__ W1, const float* __restrict__ b1,
    RngConsts rc,
    int* __restrict__ maskArr, float* __restrict__ aggAll) {
  __shared__ int   vnode[NE];
  __shared__ int   vmask[NE];
  __shared__ float xs[NE][DIN];

  const int slot = blockIdx.x;
  const int tid = threadIdx.x;
  const int wv = tid >> 6, lane = tid & 63;
  const int w = slot % NFINAL, j = slot / NFINAL;

  // Every wave redundantly recomputes the final-walk prefix (same result,
  // same cache lines) so no extra sync is needed.
  int cur = rc.starts2[w];
  int valid = 1;
  for (int t = 0; t < j; ++t)
    walk_step(nbr_dir, deg_dir, rc.maxd_dir, lane, rc.u2[t][w], cur, valid);
  if (!valid) {
    if (tid == 0) maskArr[slot] = 0;
    return;
  }
  if (tid == 0) { maskArr[slot] = 1; vnode[0] = cur; vmask[0] = 1; }
  const int n = cur;

  // 5 agg walks; wave wv < 5 handles walk p = wv; walker id = p*N + n.
  if (wv < NPATH_AGG) {
    const uint32_t wkr = (uint32_t)(wv * rc.N + n);
    int c2 = n, v2 = 1;
#pragma unroll
    for (int jj = 0; jj < MAXLEN - 1; ++jj) {
      const float u = bits_to_unif(
          jax_bits32(rc.kA[jj][0], rc.kA[jj][1], wkr, 250000u));
      walk_step(nbr_bi, deg_bi, rc.maxd_bi, lane, u, c2, v2);
      if (lane == 0) {
        vnode[1 + jj * NPATH_AGG + wv] = c2;
        vmask[1 + jj * NPATH_AGG + wv] = v2;
      }
    }
  }
  __syncthreads();

  // Stage the 16 visited x rows into LDS (coalesced-ish, batched loads).
  for (int idx = tid; idx < NE * DIN; idx += DHID) {
    const int e = idx / DIN, k = idx % DIN;
    xs[e][k] = x[(long long)vnode[e] * DIN + k];
  }
  int vm[NE];
#pragma unroll
  for (int e = 0; e < NE; ++e) vm[e] = vmask[e];
  float cntf = 5.0f;
#pragma unroll
  for (int e = 1; e < NE; ++e) cntf += (float)vm[e];
  __syncthreads();

  // fc1: hidden unit tid. LDS reads are wave-uniform broadcasts, batched.
  const float4* __restrict__ w1r = (const float4*)(W1 + (long long)tid * DIN);
  const float4* xp[NE];
#pragma unroll
  for (int e = 0; e < NE; ++e) xp[e] = (const float4*)(&xs[e][0]);

  float acc[NE];
#pragma unroll
  for (int e = 0; e < NE; ++e) acc[e] = 0.0f;
  for (int k4 = 0; k4 < DIN / 4; ++k4) {
    const float4 wv4 = w1r[k4];
#pragma unroll
    for (int e = 0; e < NE; ++e) {
      const float4 xv = xp[e][k4];
      acc[e] += wv4.x * xv.x + wv4.y * xv.y + wv4.z * xv.z + wv4.w * xv.w;
    }
  }
  const float bb = b1[tid];
  float h0 = acc[0] + bb;
  h0 = (h0 > 0.0f) ? h0 : 0.0f;
  float hs = 5.0f * h0;
#pragma unroll
  for (int e = 1; e < NE; ++e) {
    if (vm[e]) {
      const float hv = acc[e] + bb;
      hs += (hv > 0.0f) ? hv : 0.0f;
    }
  }
  aggAll[(long long)slot * DHID + tid] = hs / cntf;
}

// ---------------- Kernel B: per-output fc3 + fused masked mean -------------
// Block o: out[o] = sum_valid_slots relu(agg[s].W3[o]+b3[o]) / wsum.
__global__ __launch_bounds__(256) void k_fc3(
    const float* __restrict__ W3, const float* __restrict__ b3,
    const int* __restrict__ maskArr, const float* __restrict__ aggAll,
    float* __restrict__ out) {
  __shared__ int   maskS[NSLOT];
  __shared__ float partial[4];

  const int o = blockIdx.x;
  const int tid = threadIdx.x;
  const int wv = tid >> 6, lane = tid & 63;

  if (tid < NSLOT) maskS[tid] = maskArr[tid];
  __syncthreads();

  const float4* __restrict__ w4 = (const float4*)(W3 + (long long)o * DHID);
  const float4 g0 = w4[lane];
  const float4 g1 = w4[64 + lane];
  const float b3o = b3[o];

  float acc = 0.0f;
  for (int s = wv; s < NSLOT; s += 4) {
    if (maskS[s]) {
      const float4* a4 = (const float4*)(aggAll + (long long)s * DHID);
      const float4 a0 = a4[lane];
      const float4 a1 = a4[64 + lane];
      float p = a0.x * g0.x + a0.y * g0.y + a0.z * g0.z + a0.w * g0.w
              + a1.x * g1.x + a1.y * g1.y + a1.z * g1.z + a1.w * g1.w;
#pragma unroll
      for (int off = 32; off; off >>= 1) p += __shfl_xor(p, off);
      const float r = p + b3o;
      acc += (r > 0.0f) ? r : 0.0f;
    }
  }
  if (lane == 0) partial[wv] = acc;
  __syncthreads();
  if (tid == 0) {
    float wsum = 0.0f;
    for (int s = 0; s < NSLOT; ++s) wsum += (float)maskS[s];
    out[o] = (partial[0] + partial[1] + partial[2] + partial[3]) / wsum;
  }
}

// ---------------- Host-side PRNG chain -------------------------------------
static void h_enc(const uint32_t k[2], uint32_t x0, uint32_t x1, uint32_t out[2]) {
  tf2x32(k[0], k[1], x0, x1);
  out[0] = x0; out[1] = x1;
}
static void h_foldin(const uint32_t k[2], uint32_t data, uint32_t out[2]) {
  h_enc(k, 0u, data, out);
}

extern "C" void kernel_launch(void* const* d_in, const int* in_sizes, int n_in,
                              void* d_out, int out_size, void* d_ws, size_t ws_size,
                              hipStream_t stream) {
  const float* x       = (const float*)d_in[0];
  const int*   nbr_bi  = (const int*)d_in[2];
  const int*   deg_bi  = (const int*)d_in[3];
  const int*   nbr_dir = (const int*)d_in[4];
  const int*   deg_dir = (const int*)d_in[5];
  const float* W1      = (const float*)d_in[6];
  const float* b1      = (const float*)d_in[7];
  const float* W3      = (const float*)d_in[8];
  const float* b3      = (const float*)d_in[9];

  const int N = in_sizes[0] / DIN;
  RngConsts rc;
  rc.N = N;
  rc.maxd_bi  = in_sizes[2] / N;
  rc.maxd_dir = in_sizes[4] / N;

  const uint32_t kw[2] = {0u, 42u};            // jax.random.key(42)
  uint32_t kA[2];
  h_foldin(kw, 0u, kA);
  for (uint32_t j = 0; j < 3; ++j) h_foldin(kA, j, rc.kA[j]);

  uint32_t kS[2];
  h_foldin(kw, 1u, kS);
  uint32_t k1_[2], k2_[2];
#if JAX_THREEFRY_PARTITIONABLE
  h_enc(kS, 0u, 0u, k1_);
  h_enc(kS, 0u, 1u, k2_);
#else
  {
    uint32_t a[2], b[2];
    h_enc(kS, 0u, 2u, a);
    h_enc(kS, 1u, 3u, b);
    k1_[0] = a[0]; k1_[1] = b[0];
    k2_[0] = a[1]; k2_[1] = b[1];
  }
#endif
  {
    const uint32_t span = (uint32_t)N;
    uint32_t mult = 65536u % span;
    mult = (uint32_t)(mult * mult) % span;     // uint32 wrap, like lax.mul
    for (uint32_t i = 0; i < NFINAL; ++i) {
      const uint32_t hi = jax_bits32(k1_[0], k1_[1], i, NFINAL / 2);
      const uint32_t lo = jax_bits32(k2_[0], k2_[1], i, NFINAL / 2);
      uint32_t off = (hi % span) * mult + (lo % span);
      off %= span;
      rc.starts2[i] = (int)off;
    }
  }

  uint32_t kP[2];
  h_foldin(kw, 2u, kP);
  for (uint32_t j = 0; j < 3; ++j) {
    uint32_t kPj[2];
    h_foldin(kP, j, kPj);
    for (uint32_t i = 0; i < NFINAL; ++i)
      rc.u2[j][i] = bits_to_unif(jax_bits32(kPj[0], kPj[1], i, NFINAL / 2));
  }

  // Workspace: maskArr[40] | aggAll[40*512] floats (160 B + 80 KiB)
  int*   maskArr = (int*)d_ws;
  float* aggAll  = (float*)(maskArr + NSLOT);

  k_slot<<<NSLOT, DHID, 0, stream>>>(x, nbr_bi, deg_bi, nbr_dir, deg_dir,
                                     W1, b1, rc, maskArr, aggAll);
  k_fc3<<<DOUT, 256, 0, stream>>>(W3, b3, maskArr, aggAll, (float*)d_out);
}